// Round 9
// baseline (1350.278 us; speedup 1.0000x reference)
//
#include <hip/hip_runtime.h>
#include <stdint.h>

#define EN 120000
#define NN 12000
#define FF 768

typedef __attribute__((ext_vector_type(8))) short short8;
typedef __attribute__((ext_vector_type(4))) float floatx4;
typedef __attribute__((ext_vector_type(2))) float floatx2;
typedef __attribute__((ext_vector_type(2))) long long2v;

#ifdef __has_builtin
#if __has_builtin(__builtin_amdgcn_cvt_pk_f32_fp8) && __has_builtin(__builtin_amdgcn_cvt_f32_fp8)
#define HAS_HW_FP8 1
#endif
#if __has_builtin(__builtin_amdgcn_cvt_pk_fp8_f32)
#define HAS_HW_FP8E 1
#endif
#endif
#ifndef HAS_HW_FP8
#define HAS_HW_FP8 0
#endif
#ifndef HAS_HW_FP8E
#define HAS_HW_FP8E 0
#endif

__device__ __forceinline__ short f2b(float f) {
  union { float f; uint32_t i; } v; v.f = f;
  uint32_t r = (v.i + 0x7fffu + ((v.i >> 16) & 1u)) >> 16;
  return (short)(uint16_t)r;
}
// fp8 e4m3fn codec (OCP). Encode: HW v_cvt_pk_fp8_f32 when available; SW
// fallback exact via f32 subnormal scaling, RNE.
__device__ __forceinline__ float f8tof(uint32_t b) {
  union { uint32_t i; float f; } u;
  u.i = (b & 0x7f) << 20;
  float v = u.f * 0x1p120f;
  return (b & 0x80) ? -v : v;
}
__device__ __forceinline__ uint8_t ftof8(float v) {
#if HAS_HW_FP8E
  return (uint8_t)(__builtin_amdgcn_cvt_pk_fp8_f32(v, v, 0, false) & 0xff);
#else
  union { float f; uint32_t i; } u;
  u.f = fabsf(v) * 0x1p-120f;
  uint32_t r = (u.i + 0x7ffffu + ((u.i >> 20) & 1u)) >> 20;
  if (r > 0x7eu) r = 0x7eu;                 // clamp to 448, no inf/nan
  return (uint8_t)(r | ((v < 0.f) ? 0x80u : 0u));
#endif
}
__device__ __forceinline__ floatx2 f8pair(uint32_t u) {   // bytes 0,1
#if HAS_HW_FP8
  return __builtin_amdgcn_cvt_pk_f32_fp8(u, false);
#else
  floatx2 r; r.x = f8tof(u & 0xff); r.y = f8tof((u >> 8) & 0xff); return r;
#endif
}
__device__ __forceinline__ floatx2 f8pair_hi(uint32_t u) { // bytes 2,3
#if HAS_HW_FP8
  return __builtin_amdgcn_cvt_pk_f32_fp8(u, true);
#else
  floatx2 r; r.x = f8tof((u >> 16) & 0xff); r.y = f8tof((u >> 24) & 0xff); return r;
#endif
}
__device__ __forceinline__ float f8one(uint32_t u) {   // byte 0
#if HAS_HW_FP8
  return __builtin_amdgcn_cvt_f32_fp8(u, 0);
#else
  return f8tof(u & 0xff);
#endif
}
__device__ __forceinline__ float sigm(float x) { return 1.f / (1.f + __expf(-x)); }
__device__ __forceinline__ float tanh_fast(float x) {
  float ax = fabsf(x);
  float t = __expf(-2.f * ax);
  float r = (1.f - t) / (1.f + t);
  return copysignf(r, x);
}
__device__ __forceinline__ void async_ld16(const void* g, void* l) {
  __builtin_amdgcn_global_load_lds(
      (const __attribute__((address_space(1))) void*)g,
      (__attribute__((address_space(3))) void*)l, 16, 0, 0);
}
// fp8 K-interleave: within each 64-byte K-group, logical 8B-slot s
// (s = (k>>3)&7) is stored at byte (s&3)*16 + (s>>2)*8. One ds_read_b128 at
// quad*16 then yields lane quad's operands for BOTH K=32 MFMA halves ->
// b128 reads at the bank floor (r4: conflicts 2.4e8 -> 1.7e7).
__device__ __forceinline__ int permk(int n) {
  return (n & ~63) | (((n >> 3) & 3) << 4) | (((n >> 5) & 1) << 3) | (n & 7);
}

// ---------------------------------------------------------------------------
// Fused multi-weight GEMM: C_w[M,N] = A[M,K] @ Bt_w[N,K]^T, dtype by F8AB:
//   F8AB=0: bf16 inputs, BK=32;  F8AB=1: fp8 e4m3 inputs (K-interleaved), BK=64.
// Both stage 64-BYTE K-rows: block tile 64(M) x 128(N), LDS single-buf, 4 waves.
// Bijective XCD block swizzle (m204). Edges SORTED BY dst; sigma A-row
// permutation so each thread owns 16 CONSECUTIVE sorted edges (r8) and the
// conv epilogue does an in-register segmented scan with ~2.6 atomics/16 rows.
//
// r9 P layout (fp8, 4608 B/node), QUAD-PACKED for 1-load epilogue reads:
//   pair regions (fsT at 0, fsM at 1536): u32 at (n>>5)*64+(n&15)*4 holds
//     {f(n),s(n),f(n+16),s(n+16)}  (n bit4=0) -> f8pair / f8pair_hi decode
//   e regions (eT at 3072, eM at 3840): u16 at (n>>5)*32+(n&15)*2 holds
//     {e(n),e(n+16)} -> f8pair decode
// Pd-side values repeat within a d-run -> hoisted to run boundaries
// (loads+decodes+bias-adds issue ~5.5/16 instead of 16/16 per thread).
//
// EPI 0: store fp8 into P with the quad-packed mapping (node projections)
// EPI 1: tanh(v + bias0) -> fp8 (pre_edge -> eC, K-interleaved store)
// EPI 2: conv1 msg run-atomics into agg + gate -> e2 fp8 (NW=3: f,s,e)
// EPI 3: conv2 msg run-atomics into agg (NW=2: f,s)
// EPI 2/3 require M % 64 == 0 (true for all conv calls).
// All A/B/out strides are in BYTES. K is in elements.
// ---------------------------------------------------------------------------
template <int NW, int EPI, int F8AB>
__global__ __launch_bounds__(256, 2) void gemm_fused(
    const char* __restrict__ A, int lda,
    const char* __restrict__ Bt, int ldb, int wstride,
    int M, int K,
    void* __restrict__ outP, int ldout,
    const float* __restrict__ bias0, const float* __restrict__ bias1,
    const float* __restrict__ bias2,
    const int* __restrict__ dst, const int* __restrict__ src,
    const uint8_t* __restrict__ Pn, int pstride,
    const uint8_t* __restrict__ eInF8, uint8_t* __restrict__ e2Out,
    float* __restrict__ agg)
{
  __shared__ alignas(16) char lA[64 * 64];
  __shared__ alignas(16) char lB[NW * 128 * 64];

  const int tid  = threadIdx.x;
  const int wave = tid >> 6;
  const int lane = tid & 63;
  const int quad = lane >> 4;
  const int l16  = lane & 15;

  // ---- bijective XCD swizzle (m204 formula) ----
  const int gx  = gridDim.x;
  const int nwg = gx * gridDim.y;
  int flat = blockIdx.y * gx + blockIdx.x;
  {
    const int q = nwg >> 3, r = nwg & 7;
    const int xcd = flat & 7, lid = flat >> 3;
    flat = (xcd < r ? xcd * (q + 1) : r * (q + 1) + (xcd - r) * q) + lid;
  }
  const int mBase = (flat / gx) * 64;
  const int nBase = (flat % gx) * 128;

  floatx4 acc[NW][4][2];
#pragma unroll
  for (int w = 0; w < NW; ++w)
#pragma unroll
    for (int mt = 0; mt < 4; ++mt)
#pragma unroll
      for (int nt = 0; nt < 2; ++nt)
#pragma unroll
        for (int r = 0; r < 4; ++r) acc[w][mt][nt][r] = 0.f;

  // A staging with sigma row permutation: lA row i <- A[mBase + sigma(i)].
  // sigma(16a+4b+c) = 16b+4a+c; C-row == A-row, so output rows permute too.
  int i4 = tid >> 2;
  int am = mBase + ((i4 & 12) << 2) + ((i4 >> 4) << 2) + (i4 & 3);
  if (am > M - 1) am = M - 1;            // tail clamp (EPI 0/1 only; guarded)
  const char* aSrc = A + (size_t)am * lda + (tid & 3) * 16;

  // B staging: NW * 128 rows x 64 BYTES = NW*2 issues
  const char* bSrc[NW * 2];
#pragma unroll
  for (int i = 0; i < NW * 2; ++i) {
    int t2 = tid + i * 256;
    int w  = t2 >> 9;
    int r  = (t2 >> 2) & 127;
    bSrc[i] = Bt + (size_t)w * wstride + (size_t)(nBase + r) * ldb + (t2 & 3) * 16;
  }

  const int Kb = K * (F8AB ? 1 : 2);     // K in bytes

  for (int k0 = 0; k0 < Kb; k0 += 64) {
    __syncthreads();                     // prev iter LDS reads done
    async_ld16(aSrc + k0, lA + tid * 16);
#pragma unroll
    for (int i = 0; i < NW * 2; ++i)
      async_ld16(bSrc[i] + k0, lB + (tid + i * 256) * 16);
    __syncthreads();                     // barrier drains vmcnt -> staging done

    if constexpr (F8AB) {
      // fp8 K-interleaved: ONE b128 per fragment = {k-half0, k-half1} operands
      long2v av[4];
#pragma unroll
      for (int mt = 0; mt < 4; ++mt)
        av[mt] = *(const long2v*)(lA + (mt * 16 + l16) * 64 + quad * 16);
#pragma unroll
      for (int w = 0; w < NW; ++w)
#pragma unroll
        for (int nt = 0; nt < 2; ++nt) {
          long2v bv = *(const long2v*)(lB + (w * 128 + wave * 32 + nt * 16 + l16) * 64 + quad * 16);
#pragma unroll
          for (int mt = 0; mt < 4; ++mt) {
            acc[w][mt][nt] = __builtin_amdgcn_mfma_f32_16x16x32_fp8_fp8(
                av[mt].x, bv.x, acc[w][mt][nt], 0, 0, 0);
            acc[w][mt][nt] = __builtin_amdgcn_mfma_f32_16x16x32_fp8_fp8(
                av[mt].y, bv.y, acc[w][mt][nt], 0, 0, 0);
          }
        }
    } else {
      // bf16: one K=32 step per 64B row; frag = 16 bytes (short8)
      short8 af[4];
#pragma unroll
      for (int mt = 0; mt < 4; ++mt)
        af[mt] = *(const short8*)(lA + (mt * 16 + l16) * 64 + quad * 16);
#pragma unroll
      for (int w = 0; w < NW; ++w)
#pragma unroll
        for (int nt = 0; nt < 2; ++nt) {
          short8 bf = *(const short8*)(lB + (w * 128 + wave * 32 + nt * 16 + l16) * 64 + quad * 16);
#pragma unroll
          for (int mt = 0; mt < 4; ++mt)
            acc[w][mt][nt] = __builtin_amdgcn_mfma_f32_16x16x32_bf16(
                af[mt], bf, acc[w][mt][nt], 0, 0, 0);
        }
    }
  }

  // ---- epilogue: C/D layout col=lane&15, row=quad*4+reg [m89/m91];
  //      with sigma: global row m = mBase + quad*16 + mt*4 + r ----
  const int colW = nBase + wave * 32;

  float bb0[2], bb1[2], bb2[2];
  if (EPI == 1 || EPI == 2 || EPI == 3) {
#pragma unroll
    for (int nt = 0; nt < 2; ++nt) {
      int n = colW + nt * 16 + l16;
      bb0[nt] = bias0[n];
      if (EPI == 2 || EPI == 3) bb1[nt] = bias1[n];
      if (EPI == 2) bb2[nt] = bias2[n];
    }
  }

  if constexpr (EPI == 2 || EPI == 3) {
    // run-combined segmented reduction over 16 consecutive sorted edges,
    // with Pd-side loads/decodes hoisted to run boundaries.
    const int n0 = colW + l16;                        // bit4 == 0
    const int pOff = ((n0 >> 5) << 6) + ((n0 & 15) << 2);  // u32 in pair region
    const int eOff = ((n0 >> 5) << 5) + ((n0 & 15) << 1);  // u16 in e region
    const int pk0 = permk(n0), pk1 = permk(n0 + 16);
    const int mQ = mBase + quad * 16;
    int dp = -1;
    float run0 = 0.f, run1 = 0.f;
    float fd0 = 0.f, fd1 = 0.f, sd0 = 0.f, sd1 = 0.f, ed0 = 0.f, ed1 = 0.f;
#pragma unroll
    for (int j = 0; j < 16; ++j) {
      const int mt = j >> 2, r = j & 3;
      const int m = mQ + j;
      const int d = dst[m];
      const int s = src[m];
      if (d != dp) {
        if (dp >= 0) {
          atomicAdd(&agg[(size_t)dp * FF + n0], run0);
          atomicAdd(&agg[(size_t)dp * FF + n0 + 16], run1);
        }
        run0 = 0.f; run1 = 0.f; dp = d;
        const uint8_t* Pd = Pn + (size_t)d * pstride;
        uint32_t td = *(const uint32_t*)(Pd + pOff);
        floatx2 ta = f8pair(td), tb = f8pair_hi(td);
        fd0 = ta.x + bb0[0]; sd0 = ta.y + bb1[0];
        fd1 = tb.x + bb0[1]; sd1 = tb.y + bb1[1];
        if (EPI == 2) {
          uint32_t te = *(const unsigned short*)(Pd + 3072 + eOff);
          floatx2 ea = f8pair(te);
          ed0 = ea.x + bb2[0]; ed1 = ea.y + bb2[1];
        }
      }
      const uint8_t* Ps = Pn + (size_t)s * pstride;
      uint32_t tm = *(const uint32_t*)(Ps + 1536 + pOff);
      floatx2 ma = f8pair(tm), mb = f8pair_hi(tm);
      float hf0 = acc[0][mt][0][r] + ma.x + fd0;
      float hs0 = acc[1][mt][0][r] + ma.y + sd0;
      float hf1 = acc[0][mt][1][r] + mb.x + fd1;
      float hs1 = acc[1][mt][1][r] + mb.y + sd1;
      run0 += fmaxf(hs0, 0.f) * sigm(hf0);
      run1 += fmaxf(hs1, 0.f) * sigm(hf1);
      if (EPI == 2) {
        uint32_t me = *(const unsigned short*)(Ps + 3840 + eOff);
        floatx2 ea = f8pair(me);
        float he0 = acc[2][mt][0][r] + ea.x + ed0;
        float he1 = acc[2][mt][1][r] + ea.y + ed1;
        float ev0 = f8one(eInF8[(size_t)m * FF + pk0]);
        float ev1 = f8one(eInF8[(size_t)m * FF + pk1]);
        e2Out[(size_t)m * FF + pk0] = ftof8(ev0 * (1.f + sigm(he0)));
        e2Out[(size_t)m * FF + pk1] = ftof8(ev1 * (1.f + sigm(he1)));
      }
    }
    if (dp >= 0) {
      atomicAdd(&agg[(size_t)dp * FF + n0], run0);
      atomicAdd(&agg[(size_t)dp * FF + n0 + 16], run1);
    }
  } else {
#pragma unroll
    for (int mt = 0; mt < 4; ++mt) {
#pragma unroll
      for (int r = 0; r < 4; ++r) {
        int m = mBase + quad * 16 + mt * 4 + r;
        if (m >= M) continue;
#pragma unroll
        for (int nt = 0; nt < 2; ++nt) {
          int n = colW + nt * 16 + l16;
          float v0 = acc[0][mt][nt][r];
          if (EPI == 0) {
            // quad-packed P store (see header): q<4 -> pair regions, q>=4 -> e
            int q = n / 768, j = n - q * 768;
            int h = (j >> 4) & 1;
            size_t o;
            if (q < 4)
              o = (size_t)(((q & 1) ? 1536 : 0) + ((j >> 5) << 6) + ((j & 15) << 2)
                           + (h << 1) + ((q >> 1) & 1));
            else
              o = (size_t)((q == 4 ? 3072 : 3840) + ((j >> 5) << 5) + ((j & 15) << 1) + h);
            ((uint8_t*)outP)[(size_t)m * ldout + o] = ftof8(v0);
          } else {
            ((uint8_t*)outP)[(size_t)m * ldout + permk(n)] = ftof8(tanh_fast(v0 + bb0[nt]));
          }
        }
      }
    }
  }
}

// ---------------------------------------------------------------------------
// edge sort by dst (counting sort): hist -> exclusive scan -> scatter -> permute
__global__ void hist_k(const int* __restrict__ dst, int* __restrict__ cnt) {
  int i = blockIdx.x * 256 + threadIdx.x;
  if (i < EN) atomicAdd(&cnt[dst[i]], 1);
}

__global__ void scan_k(const int* __restrict__ cnt, int* __restrict__ off) {
  __shared__ int part[1024];
  int t = threadIdx.x;
  int base = t * 12;
  int loc[12];
  int s = 0;
#pragma unroll
  for (int j = 0; j < 12; ++j) {
    int idx = base + j;
    int c = idx < NN ? cnt[idx] : 0;
    loc[j] = s; s += c;
  }
  part[t] = s;
  __syncthreads();
  for (int d = 1; d < 1024; d <<= 1) {
    int v = (t >= d) ? part[t - d] : 0;
    __syncthreads();
    part[t] += v;
    __syncthreads();
  }
  int pre = (t == 0) ? 0 : part[t - 1];
#pragma unroll
  for (int j = 0; j < 12; ++j) {
    int idx = base + j;
    if (idx < NN) off[idx] = pre + loc[j];
  }
}

__global__ void scatter_k(const int* __restrict__ dst, int* __restrict__ off,
                          int* __restrict__ perm) {
  int i = blockIdx.x * 256 + threadIdx.x;
  if (i < EN) { int p = atomicAdd(&off[dst[i]], 1); perm[p] = i; }
}

__global__ void permute_k(const int* __restrict__ dst, const int* __restrict__ src,
                          const int* __restrict__ perm, int* __restrict__ dstS,
                          int* __restrict__ srcS) {
  int i = blockIdx.x * 256 + threadIdx.x;
  if (i < EN) { int e = perm[i]; dstS[i] = dst[e]; srcS[i] = src[e]; }
}

// gather e_raw rows in sorted edge order -> bf16 chunk (64 f32 = 256B per row)
__global__ void gather_f2b(const float* __restrict__ e_raw, const int* __restrict__ perm,
                           short* __restrict__ out, int n) {
  int i = blockIdx.x * 256 + threadIdx.x;
  if (i < n) {
    int j = i >> 6, t = i & 63;
    out[i] = f2b(e_raw[(size_t)perm[j] * 64 + t]);
  }
}

// f32 -> fp8 e4m3, K-interleaved columns (row stride FF)
__global__ void conv_f2f8(const float* __restrict__ in, uint8_t* __restrict__ out, int n) {
  int i = blockIdx.x * 256 + threadIdx.x;
  if (i < n) {
    int row = i / FF, col = i - row * FF;
    out[(size_t)row * FF + permk(col)] = ftof8(in[i]);
  }
}

// tiled transpose: in[R][C] fp32 -> out[C][R] bf16, coalesced both sides
__global__ void transpose_wt(const float* __restrict__ in, short* __restrict__ out,
                             int R, int C) {
  __shared__ float t[32][33];
  int c0 = blockIdx.x * 32, r0 = blockIdx.y * 32;
  int tx = threadIdx.x, ty = threadIdx.y;
#pragma unroll
  for (int i = ty; i < 32; i += 8)
    t[i][tx] = in[(size_t)(r0 + i) * C + (c0 + tx)];
  __syncthreads();
#pragma unroll
  for (int i = ty; i < 32; i += 8)
    out[(size_t)(c0 + i) * R + (r0 + tx)] = f2b(t[tx][i]);
}

// tiled transpose: in[R][C] fp32 -> out[C][R] fp8 e4m3, K-interleaved columns
__global__ void transpose_wt8(const float* __restrict__ in, uint8_t* __restrict__ out,
                              int R, int C) {
  __shared__ float t[32][33];
  int c0 = blockIdx.x * 32, r0 = blockIdx.y * 32;
  int tx = threadIdx.x, ty = threadIdx.y;
#pragma unroll
  for (int i = ty; i < 32; i += 8)
    t[i][tx] = in[(size_t)(r0 + i) * C + (c0 + tx)];
  __syncthreads();
#pragma unroll
  for (int i = ty; i < 32; i += 8)
    out[(size_t)(c0 + i) * R + permk(r0 + tx)] = ftof8(t[tx][i]);
}

// x1 = x + agg ; write fp8 K-ilv x1 into xF8 and fp32 back into agg (in place)
__global__ void make_x1(const float* __restrict__ x, float* __restrict__ agg,
                        uint8_t* __restrict__ x1f8, int n) {
  int i = blockIdx.x * 256 + threadIdx.x;
  if (i < n) {
    float v = x[i] + agg[i];
    agg[i] = v;
    int row = i / FF, col = i - row * FF;
    x1f8[(size_t)row * FF + permk(col)] = ftof8(v);
  }
}

// pooled = colsum(agg)   (agg holds x2)
__global__ void pool_k(const float* __restrict__ agg, float* __restrict__ pooled) {
  int t = threadIdx.x;
  int r0 = blockIdx.x * 64;
  float s0 = 0.f, s1 = 0.f, s2 = 0.f;
  for (int r = 0; r < 64; ++r) {
    int row = r0 + r;
    if (row >= NN) break;
    size_t base = (size_t)row * FF;
    s0 += agg[base + t];
    s1 += agg[base + t + 256];
    s2 += agg[base + t + 512];
  }
  atomicAdd(&pooled[t], s0);
  atomicAdd(&pooled[t + 256], s1);
  atomicAdd(&pooled[t + 512], s2);
}

__global__ void head_k(const float* __restrict__ pooled, const float* __restrict__ Wd,
                       const float* __restrict__ bd, float* __restrict__ out) {
  int l = threadIdx.x;
  int ll = l & 15;
  float a = 0.f;
  for (int j = 0; j < FF; ++j) a += pooled[j] * Wd[j * 16 + ll];
  a += bd[ll];
  float mx = a;
  for (int off = 8; off; off >>= 1) mx = fmaxf(mx, __shfl_xor(mx, off, 16));
  float ex = __expf(a - mx), sm = ex;
  for (int off = 8; off; off >>= 1) sm += __shfl_xor(sm, off, 16);
  if (l < 16) out[l] = ex / sm;
}

__global__ void sentinel_k(float* __restrict__ out, int n) {
  int i = blockIdx.x * 256 + threadIdx.x;
  if (i < n) out[i] = -1.0f;   // ws too small marker -> absmax ~2.0
}

// ---------------------------------------------------------------------------
extern "C" void kernel_launch(void* const* d_in, const int* in_sizes, int n_in,
                              void* d_out, int out_size, void* d_ws, size_t ws_size,
                              hipStream_t stream) {
  const float* x     = (const float*)d_in[0];
  const float* e_raw = (const float*)d_in[1];
  const int*   src   = (const int*)d_in[2];
  const int*   dst   = (const int*)d_in[3];
  const float* W_pre = (const float*)d_in[4];
  const float* b_pre = (const float*)d_in[5];
  const float* Wf1   = (const float*)d_in[6];
  const float* bf1   = (const float*)d_in[7];
  const float* Ws1   = (const float*)d_in[8];
  const float* bs1   = (const float*)d_in[9];
  const float* We1   = (const float*)d_in[10];
  const float* be1   = (const float*)d_in[11];
  const float* Wf2   = (const float*)d_in[12];
  const float* bf2   = (const float*)d_in[13];
  const float* Ws2   = (const float*)d_in[14];
  const float* bs2   = (const float*)d_in[15];
  const float* Wd    = (const float*)d_in[18];
  const float* bd    = (const float*)d_in[19];
  float* out = (float*)d_out;

  // ---- base workspace (ws ~256 MB measured) ----
  char* w = (char*)d_ws;
  size_t off = 0;
  auto take = [&](size_t b) -> void* {
    void* p = w + off;
    off += (b + 255) & ~(size_t)255;
    return p;
  };
  uint8_t* P    = (uint8_t*)take((size_t)NN * 4608);     // fp8 node projections (quad-packed)
  float* agg    = (float*)take((size_t)NN * FF * 4);     // agg1 -> x1 -> x2
  uint8_t* xF8  = (uint8_t*)take((size_t)NN * FF);       // x / x1 fp8 K-ilv
  uint8_t* e2   = (uint8_t*)take((size_t)EN * FF);       // e2 fp8 (sorted order, K-ilv)
  short* WpreT  = (short*)take((size_t)FF * 64 * 2);
  uint8_t* Wn1T = (uint8_t*)take((size_t)6 * FF * FF);   // [fT fM sT sM eT eM] fp8 K-ilv
  uint8_t* Wb1T = (uint8_t*)take((size_t)3 * FF * FF);   // [f s e] bottoms fp8 K-ilv
  uint8_t* Wn2T = (uint8_t*)take((size_t)4 * FF * FF);   // [f2T f2M s2T s2M] fp8 K-ilv
  uint8_t* Wb2T = (uint8_t*)take((size_t)2 * FF * FF);   // [f2 s2] bottoms fp8 K-ilv
  float* pooled = (float*)take((size_t)FF * 4);
  int* cnt      = (int*)take((size_t)NN * 4);            // dst histogram
  int* boff     = (int*)take((size_t)NN * 4);            // scatter cursors (mutated)
  int* perm     = (int*)take((size_t)EN * 4);            // sorted -> original edge
  int* dstS     = (int*)take((size_t)EN * 4);            // dst in sorted order
  int* srcS     = (int*)take((size_t)EN * 4);            // src in sorted order
  const size_t base = off;

  // ---- adaptive edge chunk (multiple of 64; 896 B/edge: erC 128 + eC 768) ----
  long long avail = (long long)ws_size - (long long)base - 4096;
  long long ecl = avail / 896;
  int Ec = (int)(ecl < 0 ? 0 : ecl);
  Ec &= ~63;
  if (Ec > EN) Ec = EN;
  if (Ec < 64 || n_in < 20) {
    sentinel_k<<<(out_size + 255) / 256, 256, 0, stream>>>(out, out_size);
    return;
  }
  short* erC   = (short*)take((size_t)Ec * 64 * 2);
  uint8_t* eC  = (uint8_t*)take((size_t)Ec * FF);        // pre_edge out, fp8 K-ilv

  hipMemsetAsync(agg, 0, (size_t)NN * FF * 4, stream);
  hipMemsetAsync(pooled, 0, (size_t)FF * 4, stream);
  hipMemsetAsync(cnt, 0, (size_t)NN * 4, stream);

  // ---- counting sort of edges by dst ----
  hist_k<<<(EN + 255) / 256, 256, 0, stream>>>(dst, cnt);
  scan_k<<<1, 1024, 0, stream>>>(cnt, boff);
  scatter_k<<<(EN + 255) / 256, 256, 0, stream>>>(dst, boff, perm);
  permute_k<<<(EN + 255) / 256, 256, 0, stream>>>(dst, src, perm, dstS, srcS);

  // x -> fp8 K-ilv
  conv_f2f8<<<(NN * FF + 255) / 256, 256, 0, stream>>>(x, xF8, NN * FF);

  // weight transposes (W[K,N] -> Wt[N,K]), tiled/coalesced
  dim3 tb(32, 8);
  transpose_wt<<<dim3(24, 2), tb, 0, stream>>>(W_pre, WpreT, 64, FF);
  const float* Wc1[3] = {Wf1, Ws1, We1};
  for (int q = 0; q < 3; ++q) {
    for (int h = 0; h < 2; ++h)
      transpose_wt8<<<dim3(24, 24), tb, 0, stream>>>(Wc1[q] + (size_t)h * FF * FF,
                                                     Wn1T + (size_t)(q * 2 + h) * FF * FF, FF, FF);
    transpose_wt8<<<dim3(24, 24), tb, 0, stream>>>(Wc1[q] + (size_t)2 * FF * FF,
                                                   Wb1T + (size_t)q * FF * FF, FF, FF);
  }
  const float* Wc2[2] = {Wf2, Ws2};
  for (int q = 0; q < 2; ++q) {
    for (int h = 0; h < 2; ++h)
      transpose_wt8<<<dim3(24, 24), tb, 0, stream>>>(Wc2[q] + (size_t)h * FF * FF,
                                                     Wn2T + (size_t)(q * 2 + h) * FF * FF, FF, FF);
    transpose_wt8<<<dim3(24, 24), tb, 0, stream>>>(Wc2[q] + (size_t)2 * FF * FF,
                                                   Wb2T + (size_t)q * FF * FF, FF, FF);
  }

  dim3 blk(256);
  const int gy_n = (NN + 63) / 64;

  // P1 = x @ [fT fM sT sM eT eM] -> P quad-packed layout (fp8 GEMM, B L2-resident)
  gemm_fused<1, 0, 1><<<dim3(36, gy_n), blk, 0, stream>>>(
      (const char*)xF8, FF, (const char*)Wn1T, FF, 0, NN, FF, P, 4608,
      nullptr, nullptr, nullptr, nullptr, nullptr, nullptr, 0, nullptr, nullptr, nullptr);

  // ---- loop 1 (sorted): pre_edge -> eC fp8; conv1 msg run-atomics + e2 ----
  for (int eo = 0; eo < EN; eo += Ec) {
    int ec = EN - eo < Ec ? EN - eo : Ec;
    gather_f2b<<<(ec * 64 + 255) / 256, 256, 0, stream>>>(e_raw, perm + eo, erC, ec * 64);
    gemm_fused<1, 1, 0><<<dim3(6, ec / 64), blk, 0, stream>>>(
        (const char*)erC, 64 * 2, (const char*)WpreT, 64 * 2, 0, ec, 64, eC, FF,
        b_pre, nullptr, nullptr, nullptr, nullptr, nullptr, 0, nullptr, nullptr, nullptr);
    gemm_fused<3, 2, 1><<<dim3(6, ec / 64), blk, 0, stream>>>(
        (const char*)eC, FF, (const char*)Wb1T, FF, FF * FF, ec, FF, nullptr, 0,
        bf1, bs1, be1, dstS + eo, srcS + eo, P, 4608,
        eC, e2 + (size_t)eo * FF, agg);
  }

  // x1 = x + agg (agg in place; x1 fp8 into xF8)
  make_x1<<<(NN * FF + 255) / 256, 256, 0, stream>>>(x, agg, xF8, NN * FF);

  // P2 = x1 @ [f2T f2M s2T s2M] -> P pair regions (fp8 GEMM)
  gemm_fused<1, 0, 1><<<dim3(24, gy_n), blk, 0, stream>>>(
      (const char*)xF8, FF, (const char*)Wn2T, FF, 0, NN, FF, P, 4608,
      nullptr, nullptr, nullptr, nullptr, nullptr, nullptr, 0, nullptr, nullptr, nullptr);

  // ---- conv2: single dispatch, A = e2 fp8 in place, msg run-atomics ----
  gemm_fused<2, 3, 1><<<dim3(6, EN / 64), blk, 0, stream>>>(
      (const char*)e2, FF, (const char*)Wb2T, FF, FF * FF, EN, FF, nullptr, 0,
      bf2, bs2, nullptr, dstS, srcS, P, 4608,
      nullptr, nullptr, agg);

  // pooled = colsum(x2)   (agg now holds x2 = x1 + agg2)
  pool_k<<<(NN + 63) / 64, blk, 0, stream>>>(agg, pooled);

  // out = softmax(pooled @ Wd + bd)
  head_k<<<1, 64, 0, stream>>>(pooled, Wd, bd, out);

  (void)in_sizes; (void)ws_size;
}

// Round 10
// 1319.196 us; speedup vs baseline: 1.0236x; 1.0236x over previous
//
#include <hip/hip_runtime.h>
#include <stdint.h>

#define EN 120000
#define NN 12000
#define FF 768

typedef __attribute__((ext_vector_type(8))) short short8;
typedef __attribute__((ext_vector_type(4))) float floatx4;
typedef __attribute__((ext_vector_type(2))) float floatx2;
typedef __attribute__((ext_vector_type(4))) int intx4;
typedef __attribute__((ext_vector_type(8))) int intx8;

#ifdef __has_builtin
#if __has_builtin(__builtin_amdgcn_cvt_pk_f32_fp8) && __has_builtin(__builtin_amdgcn_cvt_f32_fp8)
#define HAS_HW_FP8 1
#endif
#if __has_builtin(__builtin_amdgcn_cvt_pk_fp8_f32)
#define HAS_HW_FP8E 1
#endif
#endif
#ifndef HAS_HW_FP8
#define HAS_HW_FP8 0
#endif
#ifndef HAS_HW_FP8E
#define HAS_HW_FP8E 0
#endif

__device__ __forceinline__ short f2b(float f) {
  union { float f; uint32_t i; } v; v.f = f;
  uint32_t r = (v.i + 0x7fffu + ((v.i >> 16) & 1u)) >> 16;
  return (short)(uint16_t)r;
}
// fp8 e4m3fn codec (OCP). Encode: HW v_cvt_pk_fp8_f32 when available; SW
// fallback exact via f32 subnormal scaling, RNE.
__device__ __forceinline__ float f8tof(uint32_t b) {
  union { uint32_t i; float f; } u;
  u.i = (b & 0x7f) << 20;
  float v = u.f * 0x1p120f;
  return (b & 0x80) ? -v : v;
}
__device__ __forceinline__ uint8_t ftof8(float v) {
#if HAS_HW_FP8E
  return (uint8_t)(__builtin_amdgcn_cvt_pk_fp8_f32(v, v, 0, false) & 0xff);
#else
  union { float f; uint32_t i; } u;
  u.f = fabsf(v) * 0x1p-120f;
  uint32_t r = (u.i + 0x7ffffu + ((u.i >> 20) & 1u)) >> 20;
  if (r > 0x7eu) r = 0x7eu;                 // clamp to 448, no inf/nan
  return (uint8_t)(r | ((v < 0.f) ? 0x80u : 0u));
#endif
}
__device__ __forceinline__ floatx2 f8pair(uint32_t u) {   // bytes 0,1
#if HAS_HW_FP8
  return __builtin_amdgcn_cvt_pk_f32_fp8(u, false);
#else
  floatx2 r; r.x = f8tof(u & 0xff); r.y = f8tof((u >> 8) & 0xff); return r;
#endif
}
__device__ __forceinline__ floatx2 f8pair_hi(uint32_t u) { // bytes 2,3
#if HAS_HW_FP8
  return __builtin_amdgcn_cvt_pk_f32_fp8(u, true);
#else
  floatx2 r; r.x = f8tof((u >> 16) & 0xff); r.y = f8tof((u >> 24) & 0xff); return r;
#endif
}
__device__ __forceinline__ float f8one(uint32_t u) {   // byte 0
#if HAS_HW_FP8
  return __builtin_amdgcn_cvt_f32_fp8(u, 0);
#else
  return f8tof(u & 0xff);
#endif
}
__device__ __forceinline__ float sigm(float x) { return 1.f / (1.f + __expf(-x)); }
__device__ __forceinline__ float tanh_fast(float x) {
  float ax = fabsf(x);
  float t = __expf(-2.f * ax);
  float r = (1.f - t) / (1.f + t);
  return copysignf(r, x);
}
__device__ __forceinline__ void async_ld16(const void* g, void* l) {
  __builtin_amdgcn_global_load_lds(
      (const __attribute__((address_space(1))) void*)g,
      (__attribute__((address_space(3))) void*)l, 16, 0, 0);
}
// fp8 K-interleave: within each 64-byte K-group, logical 8B-slot s
// (s = (k>>3)&7) is stored at byte (s&3)*16 + (s>>2)*8. One ds_read_b128 at
// quad*16 yields lane quad's operands for both K=32 halves of the group ->
// b128 reads at the bank floor. A and B share this layout, so any consistent
// byte->k mapping inside the MFMA is correctness-preserving.
__device__ __forceinline__ int permk(int n) {
  return (n & ~63) | (((n >> 3) & 3) << 4) | (((n >> 5) & 1) << 3) | (n & 7);
}

// ---------------------------------------------------------------------------
// Fused multi-weight GEMM: C_w[M,N] = A[M,K] @ Bt_w[N,K]^T, dtype by F8AB:
//   F8AB=0: bf16 inputs, BK=32 (64B rows).
//   F8AB=1: fp8 e4m3 K-interleaved, processed as K=128 macro-steps via
//           mfma_scale_f32_16x16x128_f8f6f4 with unit scales (E8M0 127 ->
//           2^0) -> 2x MFMA rate vs non-scaled fp8 (m21/m148). B is staged
//           2-plane (both 64B groups in phase 1); A single-plane 4KB with
//           group-0 frags held in regs across the group-1 restage (keeps
//           LDS at 52/36/20KB for NW=3/2/1 -> occupancy preserved; r1/m132
//           showed 56KB+ costs a resident block).
// Block tile 64(M) x 128(N), 4 waves. Bijective XCD block swizzle (m204).
// Edges SORTED BY dst; sigma A-row permutation so each thread owns 16
// CONSECUTIVE sorted edges (r8); conv epilogue = in-register segmented scan,
// ~2.6 atomics/16 rows.
//
// r9 P layout (fp8, 4608 B/node), QUAD-PACKED for 1-load epilogue reads:
//   pair regions (fsT at 0, fsM at 1536): u32 at (n>>5)*64+(n&15)*4 holds
//     {f(n),s(n),f(n+16),s(n+16)}  (n bit4=0) -> f8pair / f8pair_hi decode
//   e regions (eT at 3072, eM at 3840): u16 at (n>>5)*32+(n&15)*2 holds
//     {e(n),e(n+16)} -> f8pair decode
// Pd-side values repeat within a d-run -> hoisted to run boundaries.
//
// EPI 0: store fp8 into P with the quad-packed mapping (node projections)
// EPI 1: tanh(v + bias0) -> fp8 (pre_edge -> eC, K-interleaved store)
// EPI 2: conv1 msg run-atomics into agg + gate -> e2 fp8 (NW=3: f,s,e)
// EPI 3: conv2 msg run-atomics into agg (NW=2: f,s)
// EPI 2/3 require M % 64 == 0 (true for all conv calls).
// All A/B/out strides are in BYTES. K is in elements; F8AB=1 needs K%128==0.
// ---------------------------------------------------------------------------
template <int NW, int EPI, int F8AB>
__global__ __launch_bounds__(256, 2) void gemm_fused(
    const char* __restrict__ A, int lda,
    const char* __restrict__ Bt, int ldb, int wstride,
    int M, int K,
    void* __restrict__ outP, int ldout,
    const float* __restrict__ bias0, const float* __restrict__ bias1,
    const float* __restrict__ bias2,
    const int* __restrict__ dst, const int* __restrict__ src,
    const uint8_t* __restrict__ Pn, int pstride,
    const uint8_t* __restrict__ eInF8, uint8_t* __restrict__ e2Out,
    float* __restrict__ agg)
{
  __shared__ alignas(16) char lA[64 * 64];
  __shared__ alignas(16) char lB[(F8AB ? NW * 2 : NW) * 128 * 64];

  const int tid  = threadIdx.x;
  const int wave = tid >> 6;
  const int lane = tid & 63;
  const int quad = lane >> 4;
  const int l16  = lane & 15;

  // ---- bijective XCD swizzle (m204 formula) ----
  const int gx  = gridDim.x;
  const int nwg = gx * gridDim.y;
  int flat = blockIdx.y * gx + blockIdx.x;
  {
    const int q = nwg >> 3, r = nwg & 7;
    const int xcd = flat & 7, lid = flat >> 3;
    flat = (xcd < r ? xcd * (q + 1) : r * (q + 1) + (xcd - r) * q) + lid;
  }
  const int mBase = (flat / gx) * 64;
  const int nBase = (flat % gx) * 128;

  floatx4 acc[NW][4][2];
#pragma unroll
  for (int w = 0; w < NW; ++w)
#pragma unroll
    for (int mt = 0; mt < 4; ++mt)
#pragma unroll
      for (int nt = 0; nt < 2; ++nt)
#pragma unroll
        for (int r = 0; r < 4; ++r) acc[w][mt][nt][r] = 0.f;

  // A staging with sigma row permutation: lA row i <- A[mBase + sigma(i)].
  // sigma(16a+4b+c) = 16b+4a+c; C-row == A-row, so output rows permute too.
  int i4 = tid >> 2;
  int am = mBase + ((i4 & 12) << 2) + ((i4 >> 4) << 2) + (i4 & 3);
  if (am > M - 1) am = M - 1;            // tail clamp (EPI 0/1 only; guarded)
  const char* aSrc = A + (size_t)am * lda + (tid & 3) * 16;

  if constexpr (F8AB) {
    // ---- fp8 K=128 macro-loop with unit-scale MX MFMA ----
    const char* bSrc2[NW * 4];
    char* bDst2[NW * 4];
#pragma unroll
    for (int i = 0; i < NW * 4; ++i) {
      int w = i >> 2, p = (i >> 1) & 1, h = i & 1;
      int row = h * 64 + (tid >> 2);
      bSrc2[i] = Bt + (size_t)w * wstride + (size_t)(nBase + row) * ldb
               + p * 64 + (tid & 3) * 16;
      bDst2[i] = lB + ((size_t)(w * 2 + p) * 128 + row) * 64 + (tid & 3) * 16;
    }
    for (int k0 = 0; k0 < K; k0 += 128) {
      __syncthreads();                   // prev iter LDS reads done
      async_ld16(aSrc + k0, lA + tid * 16);            // A group 0
#pragma unroll
      for (int i = 0; i < NW * 4; ++i)                 // B groups 0 and 1
        async_ld16(bSrc2[i] + k0, bDst2[i]);
      __syncthreads();                   // staging done (barrier drains vmcnt)

      intx4 a0[4];
#pragma unroll
      for (int mt = 0; mt < 4; ++mt)
        a0[mt] = *(const intx4*)(lA + (mt * 16 + l16) * 64 + quad * 16);

      __syncthreads();                   // all waves' a0 reads done
      async_ld16(aSrc + k0 + 64, lA + tid * 16);       // A group 1
      __syncthreads();                   // A restage done

      intx8 av8[4];
#pragma unroll
      for (int mt = 0; mt < 4; ++mt) {
        intx4 a1 = *(const intx4*)(lA + (mt * 16 + l16) * 64 + quad * 16);
        av8[mt] = __builtin_shufflevector(a0[mt], a1, 0, 1, 2, 3, 4, 5, 6, 7);
      }
#pragma unroll
      for (int w = 0; w < NW; ++w)
#pragma unroll
        for (int nt = 0; nt < 2; ++nt) {
          const char* bp = lB + ((size_t)(w * 2) * 128 + wave * 32 + nt * 16 + l16) * 64
                         + quad * 16;
          intx4 b0 = *(const intx4*)bp;
          intx4 b1 = *(const intx4*)(bp + 8192);       // plane 1 (group 1)
          intx8 bv8 = __builtin_shufflevector(b0, b1, 0, 1, 2, 3, 4, 5, 6, 7);
#pragma unroll
          for (int mt = 0; mt < 4; ++mt)
            acc[w][mt][nt] = __builtin_amdgcn_mfma_scale_f32_16x16x128_f8f6f4(
                av8[mt], bv8, acc[w][mt][nt], 0, 0,
                0, 0x7f7f7f7f, 0, 0x7f7f7f7f);         // unit scales (E8M0 127)
        }
    }
  } else {
    // ---- bf16 path: one K=32 step per 64B row ----
    const char* bSrc[NW * 2];
#pragma unroll
    for (int i = 0; i < NW * 2; ++i) {
      int t2 = tid + i * 256;
      int w  = t2 >> 9;
      int r  = (t2 >> 2) & 127;
      bSrc[i] = Bt + (size_t)w * wstride + (size_t)(nBase + r) * ldb + (t2 & 3) * 16;
    }
    const int Kb = K * 2;                // K in bytes
    for (int k0 = 0; k0 < Kb; k0 += 64) {
      __syncthreads();
      async_ld16(aSrc + k0, lA + tid * 16);
#pragma unroll
      for (int i = 0; i < NW * 2; ++i)
        async_ld16(bSrc[i] + k0, lB + (tid + i * 256) * 16);
      __syncthreads();

      short8 af[4];
#pragma unroll
      for (int mt = 0; mt < 4; ++mt)
        af[mt] = *(const short8*)(lA + (mt * 16 + l16) * 64 + quad * 16);
#pragma unroll
      for (int w = 0; w < NW; ++w)
#pragma unroll
        for (int nt = 0; nt < 2; ++nt) {
          short8 bf = *(const short8*)(lB + (w * 128 + wave * 32 + nt * 16 + l16) * 64 + quad * 16);
#pragma unroll
          for (int mt = 0; mt < 4; ++mt)
            acc[w][mt][nt] = __builtin_amdgcn_mfma_f32_16x16x32_bf16(
                af[mt], bf, acc[w][mt][nt], 0, 0, 0);
        }
    }
  }

  // ---- epilogue: C/D layout col=lane&15, row=quad*4+reg [m89/m91];
  //      with sigma: global row m = mBase + quad*16 + mt*4 + r ----
  const int colW = nBase + wave * 32;

  float bb0[2], bb1[2], bb2[2];
  if (EPI == 1 || EPI == 2 || EPI == 3) {
#pragma unroll
    for (int nt = 0; nt < 2; ++nt) {
      int n = colW + nt * 16 + l16;
      bb0[nt] = bias0[n];
      if (EPI == 2 || EPI == 3) bb1[nt] = bias1[n];
      if (EPI == 2) bb2[nt] = bias2[n];
    }
  }

  if constexpr (EPI == 2 || EPI == 3) {
    // run-combined segmented reduction over 16 consecutive sorted edges,
    // with Pd-side loads/decodes hoisted to run boundaries.
    const int n0 = colW + l16;                        // bit4 == 0
    const int pOff = ((n0 >> 5) << 6) + ((n0 & 15) << 2);  // u32 in pair region
    const int eOff = ((n0 >> 5) << 5) + ((n0 & 15) << 1);  // u16 in e region
    const int pk0 = permk(n0), pk1 = permk(n0 + 16);
    const int mQ = mBase + quad * 16;
    int dp = -1;
    float run0 = 0.f, run1 = 0.f;
    float fd0 = 0.f, fd1 = 0.f, sd0 = 0.f, sd1 = 0.f, ed0 = 0.f, ed1 = 0.f;
#pragma unroll
    for (int j = 0; j < 16; ++j) {
      const int mt = j >> 2, r = j & 3;
      const int m = mQ + j;
      const int d = dst[m];
      const int s = src[m];
      if (d != dp) {
        if (dp >= 0) {
          atomicAdd(&agg[(size_t)dp * FF + n0], run0);
          atomicAdd(&agg[(size_t)dp * FF + n0 + 16], run1);
        }
        run0 = 0.f; run1 = 0.f; dp = d;
        const uint8_t* Pd = Pn + (size_t)d * pstride;
        uint32_t td = *(const uint32_t*)(Pd + pOff);
        floatx2 ta = f8pair(td), tb = f8pair_hi(td);
        fd0 = ta.x + bb0[0]; sd0 = ta.y + bb1[0];
        fd1 = tb.x + bb0[1]; sd1 = tb.y + bb1[1];
        if (EPI == 2) {
          uint32_t te = *(const unsigned short*)(Pd + 3072 + eOff);
          floatx2 ea = f8pair(te);
          ed0 = ea.x + bb2[0]; ed1 = ea.y + bb2[1];
        }
      }
      const uint8_t* Ps = Pn + (size_t)s * pstride;
      uint32_t tm = *(const uint32_t*)(Ps + 1536 + pOff);
      floatx2 ma = f8pair(tm), mb = f8pair_hi(tm);
      float hf0 = acc[0][mt][0][r] + ma.x + fd0;
      float hs0 = acc[1][mt][0][r] + ma.y + sd0;
      float hf1 = acc[0][mt][1][r] + mb.x + fd1;
      float hs1 = acc[1][mt][1][r] + mb.y + sd1;
      run0 += fmaxf(hs0, 0.f) * sigm(hf0);
      run1 += fmaxf(hs1, 0.f) * sigm(hf1);
      if (EPI == 2) {
        uint32_t me = *(const unsigned short*)(Ps + 3840 + eOff);
        floatx2 ea = f8pair(me);
        float he0 = acc[2][mt][0][r] + ea.x + ed0;
        float he1 = acc[2][mt][1][r] + ea.y + ed1;
        float ev0 = f8one(eInF8[(size_t)m * FF + pk0]);
        float ev1 = f8one(eInF8[(size_t)m * FF + pk1]);
        e2Out[(size_t)m * FF + pk0] = ftof8(ev0 * (1.f + sigm(he0)));
        e2Out[(size_t)m * FF + pk1] = ftof8(ev1 * (1.f + sigm(he1)));
      }
    }
    if (dp >= 0) {
      atomicAdd(&agg[(size_t)dp * FF + n0], run0);
      atomicAdd(&agg[(size_t)dp * FF + n0 + 16], run1);
    }
  } else {
#pragma unroll
    for (int mt = 0; mt < 4; ++mt) {
#pragma unroll
      for (int r = 0; r < 4; ++r) {
        int m = mBase + quad * 16 + mt * 4 + r;
        if (m >= M) continue;
#pragma unroll
        for (int nt = 0; nt < 2; ++nt) {
          int n = colW + nt * 16 + l16;
          float v0 = acc[0][mt][nt][r];
          if (EPI == 0) {
            // quad-packed P store (see header): q<4 -> pair regions, q>=4 -> e
            int q = n / 768, j = n - q * 768;
            int h = (j >> 4) & 1;
            size_t o;
            if (q < 4)
              o = (size_t)(((q & 1) ? 1536 : 0) + ((j >> 5) << 6) + ((j & 15) << 2)
                           + (h << 1) + ((q >> 1) & 1));
            else
              o = (size_t)((q == 4 ? 3072 : 3840) + ((j >> 5) << 5) + ((j & 15) << 1) + h);
            ((uint8_t*)outP)[(size_t)m * ldout + o] = ftof8(v0);
          } else {
            ((uint8_t*)outP)[(size_t)m * ldout + permk(n)] = ftof8(tanh_fast(v0 + bb0[nt]));
          }
        }
      }
    }
  }
}

// ---------------------------------------------------------------------------
// edge sort by dst (counting sort): hist -> exclusive scan -> scatter -> permute
__global__ void hist_k(const int* __restrict__ dst, int* __restrict__ cnt) {
  int i = blockIdx.x * 256 + threadIdx.x;
  if (i < EN) atomicAdd(&cnt[dst[i]], 1);
}

__global__ void scan_k(const int* __restrict__ cnt, int* __restrict__ off) {
  __shared__ int part[1024];
  int t = threadIdx.x;
  int base = t * 12;
  int loc[12];
  int s = 0;
#pragma unroll
  for (int j = 0; j < 12; ++j) {
    int idx = base + j;
    int c = idx < NN ? cnt[idx] : 0;
    loc[j] = s; s += c;
  }
  part[t] = s;
  __syncthreads();
  for (int d = 1; d < 1024; d <<= 1) {
    int v = (t >= d) ? part[t - d] : 0;
    __syncthreads();
    part[t] += v;
    __syncthreads();
  }
  int pre = (t == 0) ? 0 : part[t - 1];
#pragma unroll
  for (int j = 0; j < 12; ++j) {
    int idx = base + j;
    if (idx < NN) off[idx] = pre + loc[j];
  }
}

__global__ void scatter_k(const int* __restrict__ dst, int* __restrict__ off,
                          int* __restrict__ perm) {
  int i = blockIdx.x * 256 + threadIdx.x;
  if (i < EN) { int p = atomicAdd(&off[dst[i]], 1); perm[p] = i; }
}

__global__ void permute_k(const int* __restrict__ dst, const int* __restrict__ src,
                          const int* __restrict__ perm, int* __restrict__ dstS,
                          int* __restrict__ srcS) {
  int i = blockIdx.x * 256 + threadIdx.x;
  if (i < EN) { int e = perm[i]; dstS[i] = dst[e]; srcS[i] = src[e]; }
}

// gather e_raw rows in sorted edge order -> bf16 chunk (64 f32 = 256B per row)
__global__ void gather_f2b(const float* __restrict__ e_raw, const int* __restrict__ perm,
                           short* __restrict__ out, int n) {
  int i = blockIdx.x * 256 + threadIdx.x;
  if (i < n) {
    int j = i >> 6, t = i & 63;
    out[i] = f2b(e_raw[(size_t)perm[j] * 64 + t]);
  }
}

// f32 -> fp8 e4m3, K-interleaved columns (row stride FF)
__global__ void conv_f2f8(const float* __restrict__ in, uint8_t* __restrict__ out, int n) {
  int i = blockIdx.x * 256 + threadIdx.x;
  if (i < n) {
    int row = i / FF, col = i - row * FF;
    out[(size_t)row * FF + permk(col)] = ftof8(in[i]);
  }
}

// tiled transpose: in[R][C] fp32 -> out[C][R] bf16, coalesced both sides
__global__ void transpose_wt(const float* __restrict__ in, short* __restrict__ out,
                             int R, int C) {
  __shared__ float t[32][33];
  int c0 = blockIdx.x * 32, r0 = blockIdx.y * 32;
  int tx = threadIdx.x, ty = threadIdx.y;
#pragma unroll
  for (int i = ty; i < 32; i += 8)
    t[i][tx] = in[(size_t)(r0 + i) * C + (c0 + tx)];
  __syncthreads();
#pragma unroll
  for (int i = ty; i < 32; i += 8)
    out[(size_t)(c0 + i) * R + (r0 + tx)] = f2b(t[tx][i]);
}

// tiled transpose: in[R][C] fp32 -> out[C][R] fp8 e4m3, K-interleaved columns
__global__ void transpose_wt8(const float* __restrict__ in, uint8_t* __restrict__ out,
                              int R, int C) {
  __shared__ float t[32][33];
  int c0 = blockIdx.x * 32, r0 = blockIdx.y * 32;
  int tx = threadIdx.x, ty = threadIdx.y;
#pragma unroll
  for (int i = ty; i < 32; i += 8)
    t[i][tx] = in[(size_t)(r0 + i) * C + (c0 + tx)];
  __syncthreads();
#pragma unroll
  for (int i = ty; i < 32; i += 8)
    out[(size_t)(c0 + i) * R + permk(r0 + tx)] = ftof8(t[tx][i]);
}

// x1 = x + agg ; write fp8 K-ilv x1 into xF8 and fp32 back into agg (in place)
__global__ void make_x1(const float* __restrict__ x, float* __restrict__ agg,
                        uint8_t* __restrict__ x1f8, int n) {
  int i = blockIdx.x * 256 + threadIdx.x;
  if (i < n) {
    float v = x[i] + agg[i];
    agg[i] = v;
    int row = i / FF, col = i - row * FF;
    x1f8[(size_t)row * FF + permk(col)] = ftof8(v);
  }
}

// pooled = colsum(agg)   (agg holds x2)
__global__ void pool_k(const float* __restrict__ agg, float* __restrict__ pooled) {
  int t = threadIdx.x;
  int r0 = blockIdx.x * 64;
  float s0 = 0.f, s1 = 0.f, s2 = 0.f;
  for (int r = 0; r < 64; ++r) {
    int row = r0 + r;
    if (row >= NN) break;
    size_t base = (size_t)row * FF;
    s0 += agg[base + t];
    s1 += agg[base + t + 256];
    s2 += agg[base + t + 512];
  }
  atomicAdd(&pooled[t], s0);
  atomicAdd(&pooled[t + 256], s1);
  atomicAdd(&pooled[t + 512], s2);
}

__global__ void head_k(const float* __restrict__ pooled, const float* __restrict__ Wd,
                       const float* __restrict__ bd, float* __restrict__ out) {
  int l = threadIdx.x;
  int ll = l & 15;
  float a = 0.f;
  for (int j = 0; j < FF; ++j) a += pooled[j] * Wd[j * 16 + ll];
  a += bd[ll];
  float mx = a;
  for (int off = 8; off; off >>= 1) mx = fmaxf(mx, __shfl_xor(mx, off, 16));
  float ex = __expf(a - mx), sm = ex;
  for (int off = 8; off; off >>= 1) sm += __shfl_xor(sm, off, 16);
  if (l < 16) out[l] = ex / sm;
}

__global__ void sentinel_k(float* __restrict__ out, int n) {
  int i = blockIdx.x * 256 + threadIdx.x;
  if (i < n) out[i] = -1.0f;   // ws too small marker -> absmax ~2.0
}

// ---------------------------------------------------------------------------
extern "C" void kernel_launch(void* const* d_in, const int* in_sizes, int n_in,
                              void* d_out, int out_size, void* d_ws, size_t ws_size,
                              hipStream_t stream) {
  const float* x     = (const float*)d_in[0];
  const float* e_raw = (const float*)d_in[1];
  const int*   src   = (const int*)d_in[2];
  const int*   dst   = (const int*)d_in[3];
  const float* W_pre = (const float*)d_in[4];
  const float* b_pre = (const float*)d_in[5];
  const float* Wf1   = (const float*)d_in[6];
  const float* bf1   = (const float*)d_in[7];
  const float* Ws1   = (const float*)d_in[8];
  const float* bs1   = (const float*)d_in[9];
  const float* We1   = (const float*)d_in[10];
  const float* be1   = (const float*)d_in[11];
  const float* Wf2   = (const float*)d_in[12];
  const float* bf2   = (const float*)d_in[13];
  const float* Ws2   = (const float*)d_in[14];
  const float* bs2   = (const float*)d_in[15];
  const float* Wd    = (const float*)d_in[18];
  const float* bd    = (const float*)d_in[19];
  float* out = (float*)d_out;

  // ---- base workspace (ws ~256 MB measured) ----
  char* w = (char*)d_ws;
  size_t off = 0;
  auto take = [&](size_t b) -> void* {
    void* p = w + off;
    off += (b + 255) & ~(size_t)255;
    return p;
  };
  uint8_t* P    = (uint8_t*)take((size_t)NN * 4608);     // fp8 node projections (quad-packed)
  float* agg    = (float*)take((size_t)NN * FF * 4);     // agg1 -> x1 -> x2
  uint8_t* xF8  = (uint8_t*)take((size_t)NN * FF);       // x / x1 fp8 K-ilv
  uint8_t* e2   = (uint8_t*)take((size_t)EN * FF);       // e2 fp8 (sorted order, K-ilv)
  short* WpreT  = (short*)take((size_t)FF * 64 * 2);
  uint8_t* Wn1T = (uint8_t*)take((size_t)6 * FF * FF);   // [fT fM sT sM eT eM] fp8 K-ilv
  uint8_t* Wb1T = (uint8_t*)take((size_t)3 * FF * FF);   // [f s e] bottoms fp8 K-ilv
  uint8_t* Wn2T = (uint8_t*)take((size_t)4 * FF * FF);   // [f2T f2M s2T s2M] fp8 K-ilv
  uint8_t* Wb2T = (uint8_t*)take((size_t)2 * FF * FF);   // [f2 s2] bottoms fp8 K-ilv
  float* pooled = (float*)take((size_t)FF * 4);
  int* cnt      = (int*)take((size_t)NN * 4);            // dst histogram
  int* boff     = (int*)take((size_t)NN * 4);            // scatter cursors (mutated)
  int* perm     = (int*)take((size_t)EN * 4);            // sorted -> original edge
  int* dstS     = (int*)take((size_t)EN * 4);            // dst in sorted order
  int* srcS     = (int*)take((size_t)EN * 4);            // src in sorted order
  const size_t base = off;

  // ---- adaptive edge chunk (multiple of 64; 896 B/edge: erC 128 + eC 768) ----
  long long avail = (long long)ws_size - (long long)base - 4096;
  long long ecl = avail / 896;
  int Ec = (int)(ecl < 0 ? 0 : ecl);
  Ec &= ~63;
  if (Ec > EN) Ec = EN;
  if (Ec < 64 || n_in < 20) {
    sentinel_k<<<(out_size + 255) / 256, 256, 0, stream>>>(out, out_size);
    return;
  }
  short* erC   = (short*)take((size_t)Ec * 64 * 2);
  uint8_t* eC  = (uint8_t*)take((size_t)Ec * FF);        // pre_edge out, fp8 K-ilv

  hipMemsetAsync(agg, 0, (size_t)NN * FF * 4, stream);
  hipMemsetAsync(pooled, 0, (size_t)FF * 4, stream);
  hipMemsetAsync(cnt, 0, (size_t)NN * 4, stream);

  // ---- counting sort of edges by dst ----
  hist_k<<<(EN + 255) / 256, 256, 0, stream>>>(dst, cnt);
  scan_k<<<1, 1024, 0, stream>>>(cnt, boff);
  scatter_k<<<(EN + 255) / 256, 256, 0, stream>>>(dst, boff, perm);
  permute_k<<<(EN + 255) / 256, 256, 0, stream>>>(dst, src, perm, dstS, srcS);

  // x -> fp8 K-ilv
  conv_f2f8<<<(NN * FF + 255) / 256, 256, 0, stream>>>(x, xF8, NN * FF);

  // weight transposes (W[K,N] -> Wt[N,K]), tiled/coalesced
  dim3 tb(32, 8);
  transpose_wt<<<dim3(24, 2), tb, 0, stream>>>(W_pre, WpreT, 64, FF);
  const float* Wc1[3] = {Wf1, Ws1, We1};
  for (int q = 0; q < 3; ++q) {
    for (int h = 0; h < 2; ++h)
      transpose_wt8<<<dim3(24, 24), tb, 0, stream>>>(Wc1[q] + (size_t)h * FF * FF,
                                                     Wn1T + (size_t)(q * 2 + h) * FF * FF, FF, FF);
    transpose_wt8<<<dim3(24, 24), tb, 0, stream>>>(Wc1[q] + (size_t)2 * FF * FF,
                                                   Wb1T + (size_t)q * FF * FF, FF, FF);
  }
  const float* Wc2[2] = {Wf2, Ws2};
  for (int q = 0; q < 2; ++q) {
    for (int h = 0; h < 2; ++h)
      transpose_wt8<<<dim3(24, 24), tb, 0, stream>>>(Wc2[q] + (size_t)h * FF * FF,
                                                     Wn2T + (size_t)(q * 2 + h) * FF * FF, FF, FF);
    transpose_wt8<<<dim3(24, 24), tb, 0, stream>>>(Wc2[q] + (size_t)2 * FF * FF,
                                                   Wb2T + (size_t)q * FF * FF, FF, FF);
  }

  dim3 blk(256);
  const int gy_n = (NN + 63) / 64;

  // P1 = x @ [fT fM sT sM eT eM] -> P quad-packed layout (fp8 MX GEMM)
  gemm_fused<1, 0, 1><<<dim3(36, gy_n), blk, 0, stream>>>(
      (const char*)xF8, FF, (const char*)Wn1T, FF, 0, NN, FF, P, 4608,
      nullptr, nullptr, nullptr, nullptr, nullptr, nullptr, 0, nullptr, nullptr, nullptr);

  // ---- loop 1 (sorted): pre_edge -> eC fp8; conv1 msg run-atomics + e2 ----
  for (int eo = 0; eo < EN; eo += Ec) {
    int ec = EN - eo < Ec ? EN - eo : Ec;
    gather_f2b<<<(ec * 64 + 255) / 256, 256, 0, stream>>>(e_raw, perm + eo, erC, ec * 64);
    gemm_fused<1, 1, 0><<<dim3(6, ec / 64), blk, 0, stream>>>(
        (const char*)erC, 64 * 2, (const char*)WpreT, 64 * 2, 0, ec, 64, eC, FF,
        b_pre, nullptr, nullptr, nullptr, nullptr, nullptr, 0, nullptr, nullptr, nullptr);
    gemm_fused<3, 2, 1><<<dim3(6, ec / 64), blk, 0, stream>>>(
        (const char*)eC, FF, (const char*)Wb1T, FF, FF * FF, ec, FF, nullptr, 0,
        bf1, bs1, be1, dstS + eo, srcS + eo, P, 4608,
        eC, e2 + (size_t)eo * FF, agg);
  }

  // x1 = x + agg (agg in place; x1 fp8 into xF8)
  make_x1<<<(NN * FF + 255) / 256, 256, 0, stream>>>(x, agg, xF8, NN * FF);

  // P2 = x1 @ [f2T f2M s2T s2M] -> P pair regions (fp8 MX GEMM)
  gemm_fused<1, 0, 1><<<dim3(24, gy_n), blk, 0, stream>>>(
      (const char*)xF8, FF, (const char*)Wn2T, FF, 0, NN, FF, P, 4608,
      nullptr, nullptr, nullptr, nullptr, nullptr, nullptr, 0, nullptr, nullptr, nullptr);

  // ---- conv2: single dispatch, A = e2 fp8 in place, msg run-atomics ----
  gemm_fused<2, 3, 1><<<dim3(6, EN / 64), blk, 0, stream>>>(
      (const char*)e2, FF, (const char*)Wb2T, FF, FF * FF, EN, FF, nullptr, 0,
      bf2, bs2, nullptr, dstS, srcS, P, 4608,
      nullptr, nullptr, agg);

  // pooled = colsum(x2)   (agg now holds x2 = x1 + agg2)
  pool_k<<<(NN + 63) / 64, blk, 0, stream>>>(agg, pooled);

  // out = softmax(pooled @ Wd + bd)
  head_k<<<1, 64, 0, stream>>>(pooled, Wd, bd, out);

  (void)in_sizes; (void)ws_size;
}